// Round 19
// baseline (138.132 us; speedup 1.0000x reference)
//
#include <hip/hip_runtime.h>
#include <stdint.h>

static constexpr uint32_t SEQN = 4194304u;
static constexpr uint32_t BINS = 65536u;
static constexpr uint32_t QWORDS = BINS / 4u;       // u8x4-packed words (16384)
static constexpr uint32_t NBLK = 256u;              // 1 block/CU, 16 waves
static constexpr uint32_t NTHR = 1024u;
static constexpr uint32_t ROWS_PER_BLK = SEQN / NBLK;  // 16384 (u8-safe: lambda=0.25)

// ---------- histogram: batch-8 loads + DPP keys; dumps partial + per-chunk sums ----------
// chunk = 256 bins = 64 words; 256 chunks total.
__global__ __launch_bounds__(NTHR) void k_hist_lds(const float4* __restrict__ in4,
                                                   uint32_t* __restrict__ partial,
                                                   uint32_t* __restrict__ chunkSum) {
  __shared__ __align__(16) uint32_t h[QWORDS];  // 64 KiB u8x4 counters
  __shared__ uint32_t gsum[256];
  uint32_t tid = threadIdx.x, blk = blockIdx.x;
  uint4* hv = (uint4*)h;
  for (uint32_t i = tid; i < QWORDS / 4u; i += NTHR) hv[i] = make_uint4(0u, 0u, 0u, 0u);
  if (tid < 256u) gsum[tid] = 0u;
  __syncthreads();
  uint32_t q = tid & 3u;
  uint32_t shift = 12u - (q << 2);        // quad q covers bits [4q,4q+4) MSB-first
  bool leader = (q == 0u);
  const float4* base = in4 + (size_t)blk * (ROWS_PER_BLK * 4u);
#pragma unroll
  for (uint32_t b = 0; b < 8u; ++b) {
    float4 v[8];
#pragma unroll
    for (uint32_t u = 0; u < 8u; ++u)       // 8 independent coalesced 16B loads
      v[u] = base[(size_t)(b * 8u + u) * NTHR + tid];
#pragma unroll
    for (uint32_t u = 0; u < 8u; ++u) {
      float nf = ((v[u].x * 2.0f + v[u].y) * 2.0f + v[u].z) * 2.0f + v[u].w;
      uint32_t part = ((uint32_t)nf) << shift;
      uint32_t s1 = part + (uint32_t)__builtin_amdgcn_mov_dpp((int)part, 0xB1, 0xF, 0xF, true);
      uint32_t key = s1 + (uint32_t)__builtin_amdgcn_mov_dpp((int)s1, 0x4E, 0xF, 0xF, true);
      if (leader) atomicAdd(&h[key >> 2], 1u << ((key & 3u) << 3));
    }
  }
  __syncthreads();
  uint4* dst = (uint4*)(partial + (size_t)blk * QWORDS);
  for (uint32_t i = tid; i < QWORDS / 4u; i += NTHR) dst[i] = hv[i];
  // epilogue: per-chunk sums (thread sums 16 words = 64 bins; 4 threads per chunk)
  uint32_t wsum = 0u;
#pragma unroll
  for (uint32_t i = 0; i < 16u; ++i) {
    uint32_t v = h[tid * 16u + i];
    wsum += (v & 0x00FF00FFu) + ((v >> 8) & 0x00FF00FFu);
  }
  wsum = (wsum & 0xFFFFu) + (wsum >> 16);
  atomicAdd(&gsum[tid >> 2], wsum);
  __syncthreads();
  if (tid < 256u) chunkSum[blk * 256u + tid] = gsum[tid];
}

// ---------- full-width fused reduce+scan: 256 blocks x 256 thr -> offs ----------
__global__ __launch_bounds__(256) void k_redscan2(const uint32_t* __restrict__ partial,
                                                  const uint32_t* __restrict__ chunkSum,
                                                  uint32_t* __restrict__ offs) {
  __shared__ uint32_t tot[256];
  __shared__ uint32_t sc[256];
  __shared__ uint2 acc[4][64];
  __shared__ uint32_t wt[4];
  uint32_t tid = threadIdx.x, b = blockIdx.x;
  // (1) chunk totals via coalesced row sweep of chunkSum[256][256] (L2-hot)
  uint32_t t = 0u;
#pragma unroll 8
  for (uint32_t p = 0; p < 256u; ++p) t += chunkSum[p * 256u + tid];
  tot[tid] = t;
  __syncthreads();
  {  // block exclusive scan of tot -> sc
    uint32_t lane = tid & 63u, wid = tid >> 6;
    uint32_t v = tot[tid], incl = v;
    for (int d = 1; d < 64; d <<= 1) {
      uint32_t n = __shfl_up(incl, d, 64);
      if (lane >= (uint32_t)d) incl += n;
    }
    if (lane == 63u) wt[wid] = incl;
    __syncthreads();
    uint32_t wbase = 0u;
    for (uint32_t w = 0; w < wid; ++w) wbase += wt[w];
    sc[tid] = wbase + incl - v;  // exclusive prefix
  }
  __syncthreads();
  uint32_t base0 = sc[b];  // global row base of chunk b
  // (2) reduce chunk b's 64 words across 256 partials
  uint32_t wl = tid & 63u, g = tid >> 6;
  uint32_t w = b * 64u + wl;
  uint32_t e = 0u, o = 0u;  // packed u16 pairs; 64*255 < 65536
  uint32_t p0 = g * 64u;
#pragma unroll 8
  for (uint32_t p = p0; p < p0 + 64u; ++p) {
    uint32_t v = partial[(size_t)p * QWORDS + w];
    e += v & 0x00FF00FFu;
    o += (v >> 8) & 0x00FF00FFu;
  }
  acc[g][wl] = make_uint2(e, o);
  __syncthreads();
  // (3) wave 0: combine, unpack, scan 256 bins, write offs
  if (tid < 64u) {
    uint2 a0 = acc[0][tid], a1 = acc[1][tid], a2 = acc[2][tid], a3 = acc[3][tid];
    uint32_t E = a0.x + a1.x + a2.x + a3.x;
    uint32_t O = a0.y + a1.y + a2.y + a3.y;
    uint32_t c0 = E & 0xFFFFu, c2 = E >> 16, c1 = O & 0xFFFFu, c3 = O >> 16;
    uint32_t ssum = c0 + c1 + c2 + c3;
    uint32_t incl = ssum;
    for (int d = 1; d < 64; d <<= 1) {
      uint32_t n = __shfl_up(incl, d, 64);
      if (tid >= (uint32_t)d) incl += n;
    }
    uint32_t base = base0 + (incl - ssum);
    ((uint4*)offs)[w] = make_uint4(base, base + c0, base + c0 + c1,
                                   base + c0 + c1 + c2);
  }
}

// ---------- fallback global-atomic histogram (small ws) ----------
__global__ __launch_bounds__(256) void k_zero(uint32_t* __restrict__ hist,
                                              uint32_t* __restrict__ blkTot) {
  uint32_t i = blockIdx.x * 256u + threadIdx.x;
  if (i < BINS) hist[i] = 0u;
  if (i < 64u) blkTot[i] = 0u;
}

__global__ __launch_bounds__(256) void k_hist(const float4* __restrict__ in4,
                                              uint32_t* __restrict__ hist) {
  uint32_t r = blockIdx.x * 256u + threadIdx.x;
  if (r >= SEQN) return;
  uint32_t key = 0u;
#pragma unroll
  for (uint32_t qq = 0; qq < 4u; ++qq) {
    float4 v = in4[(size_t)r * 4u + qq];
    uint32_t nib = ((uint32_t)v.x << 3) | ((uint32_t)v.y << 2) |
                   ((uint32_t)v.z << 1) | (uint32_t)v.w;
    key = (key << 4) | nib;
  }
  atomicAdd(&hist[key], 1u);
}

__global__ __launch_bounds__(256) void k_scan1(const uint32_t* __restrict__ hist,
                                               uint32_t* __restrict__ blkTot) {
  uint32_t tid = threadIdx.x, blk = blockIdx.x;
  uint32_t b0 = blk * 1024u + tid * 4u;
  uint32_t s = hist[b0] + hist[b0 + 1] + hist[b0 + 2] + hist[b0 + 3];
  for (int d = 1; d < 64; d <<= 1) s += __shfl_xor(s, d, 64);
  __shared__ uint32_t wt[4];
  if ((tid & 63u) == 0u) wt[tid >> 6] = s;
  __syncthreads();
  if (tid == 0u) blkTot[blk] = wt[0] + wt[1] + wt[2] + wt[3];
}

__global__ __launch_bounds__(256) void k_scanB(const uint32_t* __restrict__ hist,
                                               const uint32_t* __restrict__ blkTot,
                                               uint32_t* __restrict__ offs) {
  __shared__ uint32_t s_base;
  __shared__ uint32_t wt[4];
  uint32_t tid = threadIdx.x, blk = blockIdx.x;
  if (tid < 64u) {
    uint32_t v = blkTot[tid];
    uint32_t incl = v;
    for (int d = 1; d < 64; d <<= 1) {
      uint32_t n = __shfl_up(incl, d, 64);
      if (tid >= (uint32_t)d) incl += n;
    }
    if (tid == blk) s_base = incl - v;
  }
  __syncthreads();
  uint32_t lane = tid & 63u, wid = tid >> 6;
  uint32_t b0 = blk * 1024u + tid * 4u;
  uint4 c = ((const uint4*)hist)[b0 >> 2];
  uint32_t s = c.x + c.y + c.z + c.w;
  uint32_t incl = s;
  for (int d = 1; d < 64; d <<= 1) {
    uint32_t n = __shfl_up(incl, d, 64);
    if (lane >= (uint32_t)d) incl += n;
  }
  if (lane == 63u) wt[wid] = incl;
  __syncthreads();
  uint32_t wbase = 0u;
  for (uint32_t w = 0; w < wid; ++w) wbase += wt[w];
  uint32_t base = s_base + wbase + (incl - s);
  ((uint4*)offs)[b0 >> 2] = make_uint4(base, base + c.x, base + c.x + c.y,
                                       base + c.x + c.y + c.z);
}

// ---------- range-walk writer: dense stores over each wave's 8-key union ----------
__global__ __launch_bounds__(256) void k_write_range(const uint32_t* __restrict__ offs,
                                                     float4* __restrict__ out4) {
  __shared__ uint32_t s_off[33];
  uint32_t tid = threadIdx.x, blk = blockIdx.x;
  if (tid < 33u) {
    uint32_t k = blk * 32u + tid;
    s_off[tid] = (k < BINS) ? offs[k] : SEQN;
  }
  __syncthreads();
  uint32_t lane = tid & 63u, wid = tid >> 6;
  uint32_t kbase = blk * 32u + wid * 8u;
  uint32_t q0 = s_off[wid * 8u] * 4u;         // multiple of 4 -> g&3 == lane&3 forever
  uint32_t q8 = s_off[wid * 8u + 8u] * 4u;
  uint32_t b1 = s_off[wid * 8u + 1u] * 4u, b2 = s_off[wid * 8u + 2u] * 4u;
  uint32_t b3 = s_off[wid * 8u + 3u] * 4u, b4 = s_off[wid * 8u + 4u] * 4u;
  uint32_t b5 = s_off[wid * 8u + 5u] * 4u, b6 = s_off[wid * 8u + 6u] * 4u;
  uint32_t b7 = s_off[wid * 8u + 7u] * 4u;
  uint32_t sh = 12u - ((lane & 3u) << 2);
  for (uint32_t g = q0 + lane; g < q8; g += 64u) {
    uint32_t kl = (uint32_t)(g >= b1) + (uint32_t)(g >= b2) + (uint32_t)(g >= b3) +
                  (uint32_t)(g >= b4) + (uint32_t)(g >= b5) + (uint32_t)(g >= b6) +
                  (uint32_t)(g >= b7);
    uint32_t key = kbase + kl;
    uint32_t nib = (key >> sh) & 15u;
    float4 pat;
    pat.x = (float)((nib >> 3) & 1u);
    pat.y = (float)((nib >> 2) & 1u);
    pat.z = (float)((nib >> 1) & 1u);
    pat.w = (float)(nib & 1u);
    out4[g] = pat;
  }
}

extern "C" void kernel_launch(void* const* d_in, const int* in_sizes, int n_in,
                              void* d_out, int out_size, void* d_ws, size_t ws_size,
                              hipStream_t stream) {
  const float4* in4 = (const float4*)d_in[0];
  float4* out4 = (float4*)d_out;
  uint32_t* hist = (uint32_t*)d_ws;               // 65536 u32 (fallback only)
  uint32_t* offs = hist + BINS;                   // 65536 u32
  uint32_t* blkTot = offs + BINS;                 // 1024 u32 (fallback only)
  uint32_t* partial = blkTot + 1024u;             // NBLK * QWORDS u32 = 16 MiB
  uint32_t* chunkSum = partial + (size_t)NBLK * QWORDS;  // 256*256 u32 = 256 KiB

  size_t need = ((size_t)2 * BINS + 1024u + (size_t)NBLK * QWORDS + NBLK * 256u) * 4u;
  if (ws_size >= need) {
    k_hist_lds<<<NBLK, NTHR, 0, stream>>>(in4, partial, chunkSum);
    k_redscan2<<<256, 256, 0, stream>>>(partial, chunkSum, offs);
  } else {
    k_zero<<<BINS / 256, 256, 0, stream>>>(hist, blkTot);
    k_hist<<<SEQN / 256, 256, 0, stream>>>(in4, hist);
    k_scan1<<<64, 256, 0, stream>>>(hist, blkTot);
    k_scanB<<<64, 256, 0, stream>>>(hist, blkTot, offs);
  }
  k_write_range<<<BINS / 32, 256, 0, stream>>>(offs, out4);
}

// Round 20
// 132.707 us; speedup vs baseline: 1.0409x; 1.0409x over previous
//
#include <hip/hip_runtime.h>
#include <stdint.h>

static constexpr uint32_t SEQN = 4194304u;
static constexpr uint32_t BINS = 65536u;
static constexpr uint32_t QWORDS = BINS / 4u;       // u8x4-packed words (16384)
static constexpr uint32_t NBLK = 256u;              // 1 block/CU, 16 waves
static constexpr uint32_t NTHR = 1024u;
static constexpr uint32_t ROWS_PER_BLK = SEQN / NBLK;  // 16384 (u8-safe: lambda=0.25)

// ---------- histogram: batch-8 loads + DPP keys; dumps partial + per-group sums ----------
__global__ __launch_bounds__(NTHR) void k_hist_lds(const float4* __restrict__ in4,
                                                   uint32_t* __restrict__ partial,
                                                   uint32_t* __restrict__ groupSum) {
  __shared__ __align__(16) uint32_t h[QWORDS];  // 64 KiB u8x4 counters
  __shared__ uint32_t gsum[64];
  uint32_t tid = threadIdx.x, blk = blockIdx.x;
  uint4* hv = (uint4*)h;
  for (uint32_t i = tid; i < QWORDS / 4u; i += NTHR) hv[i] = make_uint4(0u, 0u, 0u, 0u);
  if (tid < 64u) gsum[tid] = 0u;
  __syncthreads();
  uint32_t q = tid & 3u;
  uint32_t shift = 12u - (q << 2);        // quad q covers bits [4q,4q+4) MSB-first
  bool leader = (q == 0u);
  const float4* base = in4 + (size_t)blk * (ROWS_PER_BLK * 4u);
#pragma unroll
  for (uint32_t b = 0; b < 8u; ++b) {
    float4 v[8];
#pragma unroll
    for (uint32_t u = 0; u < 8u; ++u)       // 8 independent coalesced 16B loads
      v[u] = base[(size_t)(b * 8u + u) * NTHR + tid];
#pragma unroll
    for (uint32_t u = 0; u < 8u; ++u) {
      float nf = ((v[u].x * 2.0f + v[u].y) * 2.0f + v[u].z) * 2.0f + v[u].w;
      uint32_t part = ((uint32_t)nf) << shift;
      uint32_t s1 = part + (uint32_t)__builtin_amdgcn_mov_dpp((int)part, 0xB1, 0xF, 0xF, true);
      uint32_t key = s1 + (uint32_t)__builtin_amdgcn_mov_dpp((int)s1, 0x4E, 0xF, 0xF, true);
      if (leader) atomicAdd(&h[key >> 2], 1u << ((key & 3u) << 3));
    }
  }
  __syncthreads();
  uint4* dst = (uint4*)(partial + (size_t)blk * QWORDS);
  for (uint32_t i = tid; i < QWORDS / 4u; i += NTHR) dst[i] = hv[i];
  // epilogue: per-group sums (group = 1024 bins = 256 words; thread sums 16 words)
  uint32_t wsum = 0u;
#pragma unroll
  for (uint32_t i = 0; i < 16u; ++i) {
    uint32_t v = h[tid * 16u + i];
    wsum += (v & 0x00FF00FFu) + ((v >> 8) & 0x00FF00FFu);  // <= 16*510 per u16 lane
  }
  wsum = (wsum & 0xFFFFu) + (wsum >> 16);
  atomicAdd(&gsum[tid >> 4], wsum);
  __syncthreads();
  if (tid < 64u) groupSum[blk * 64u + tid] = gsum[tid];
}

// ---------- fused reduce + scan: partial+groupSum -> offs (64 blocks x 1024) ----------
__global__ __launch_bounds__(NTHR) void k_redscan(const uint32_t* __restrict__ partial,
                                                  const uint32_t* __restrict__ groupSum,
                                                  uint32_t* __restrict__ offs) {
  __shared__ uint2 acc[4][256];
  __shared__ uint32_t gpart[16][64];
  __shared__ uint32_t s_base;
  __shared__ uint32_t wt[4];
  uint32_t tid = threadIdx.x, g = blockIdx.x;
  // group totals: 16 chunks x 16 rows of groupSum[256][64]
  uint32_t col = tid & 63u, chunk = tid >> 6;
  uint32_t gs = 0u;
#pragma unroll
  for (uint32_t r = 0; r < 16u; ++r) gs += groupSum[(chunk * 16u + r) * 64u + col];
  gpart[chunk][col] = gs;
  // reduce this block's 256 words across 256 partials (4 groups x 64)
  uint32_t wl = tid & 255u, grp = tid >> 8;
  uint32_t w = g * 256u + wl;
  uint32_t e = 0u, o = 0u;  // packed u16 pairs; 64*255 < 65536
  uint32_t p0 = grp * 64u;
#pragma unroll 8
  for (uint32_t p = p0; p < p0 + 64u; ++p) {
    uint32_t v = partial[(size_t)p * QWORDS + w];
    e += v & 0x00FF00FFu;
    o += (v >> 8) & 0x00FF00FFu;
  }
  acc[grp][wl] = make_uint2(e, o);
  __syncthreads();
  uint32_t c0 = 0, c1 = 0, c2 = 0, c3 = 0, ssum = 0, incl = 0;
  uint32_t lane = tid & 63u, wid = tid >> 6;
  if (tid < 64u) {  // block base: exclusive prefix of 64 group totals
    uint32_t t = 0u;
#pragma unroll
    for (uint32_t i = 0; i < 16u; ++i) t += gpart[i][tid];
    uint32_t ti = t;
    for (int d = 1; d < 64; d <<= 1) {
      uint32_t n = __shfl_up(ti, d, 64);
      if (tid >= (uint32_t)d) ti += n;
    }
    if (tid == g) s_base = ti - t;
  }
  if (tid < 256u) {  // combine 4 groups, per-word counts, 4-wave scan
    uint2 a0 = acc[0][wl], a1 = acc[1][wl], a2 = acc[2][wl], a3 = acc[3][wl];
    uint32_t E = a0.x + a1.x + a2.x + a3.x;
    uint32_t O = a0.y + a1.y + a2.y + a3.y;
    c0 = E & 0xFFFFu; c2 = E >> 16; c1 = O & 0xFFFFu; c3 = O >> 16;
    ssum = c0 + c1 + c2 + c3;
    incl = ssum;
    for (int d = 1; d < 64; d <<= 1) {
      uint32_t n = __shfl_up(incl, d, 64);
      if (lane >= (uint32_t)d) incl += n;
    }
    if (lane == 63u) wt[wid] = incl;
  }
  __syncthreads();
  if (tid < 256u) {
    uint32_t wbase = 0u;
    for (uint32_t ww = 0; ww < wid; ++ww) wbase += wt[ww];
    uint32_t base = s_base + wbase + (incl - ssum);
    ((uint4*)offs)[w] = make_uint4(base, base + c0, base + c0 + c1,
                                   base + c0 + c1 + c2);
  }
}

// ---------- fallback global-atomic histogram (small ws) ----------
__global__ __launch_bounds__(256) void k_zero(uint32_t* __restrict__ hist,
                                              uint32_t* __restrict__ blkTot) {
  uint32_t i = blockIdx.x * 256u + threadIdx.x;
  if (i < BINS) hist[i] = 0u;
  if (i < 64u) blkTot[i] = 0u;
}

__global__ __launch_bounds__(256) void k_hist(const float4* __restrict__ in4,
                                              uint32_t* __restrict__ hist) {
  uint32_t r = blockIdx.x * 256u + threadIdx.x;
  if (r >= SEQN) return;
  uint32_t key = 0u;
#pragma unroll
  for (uint32_t qq = 0; qq < 4u; ++qq) {
    float4 v = in4[(size_t)r * 4u + qq];
    uint32_t nib = ((uint32_t)v.x << 3) | ((uint32_t)v.y << 2) |
                   ((uint32_t)v.z << 1) | (uint32_t)v.w;
    key = (key << 4) | nib;
  }
  atomicAdd(&hist[key], 1u);
}

__global__ __launch_bounds__(256) void k_scan1(const uint32_t* __restrict__ hist,
                                               uint32_t* __restrict__ blkTot) {
  uint32_t tid = threadIdx.x, blk = blockIdx.x;
  uint32_t b0 = blk * 1024u + tid * 4u;
  uint32_t s = hist[b0] + hist[b0 + 1] + hist[b0 + 2] + hist[b0 + 3];
  for (int d = 1; d < 64; d <<= 1) s += __shfl_xor(s, d, 64);
  __shared__ uint32_t wt[4];
  if ((tid & 63u) == 0u) wt[tid >> 6] = s;
  __syncthreads();
  if (tid == 0u) blkTot[blk] = wt[0] + wt[1] + wt[2] + wt[3];
}

__global__ __launch_bounds__(256) void k_scanB(const uint32_t* __restrict__ hist,
                                               const uint32_t* __restrict__ blkTot,
                                               uint32_t* __restrict__ offs) {
  __shared__ uint32_t s_base;
  __shared__ uint32_t wt[4];
  uint32_t tid = threadIdx.x, blk = blockIdx.x;
  if (tid < 64u) {
    uint32_t v = blkTot[tid];
    uint32_t incl = v;
    for (int d = 1; d < 64; d <<= 1) {
      uint32_t n = __shfl_up(incl, d, 64);
      if (tid >= (uint32_t)d) incl += n;
    }
    if (tid == blk) s_base = incl - v;
  }
  __syncthreads();
  uint32_t lane = tid & 63u, wid = tid >> 6;
  uint32_t b0 = blk * 1024u + tid * 4u;
  uint4 c = ((const uint4*)hist)[b0 >> 2];
  uint32_t s = c.x + c.y + c.z + c.w;
  uint32_t incl = s;
  for (int d = 1; d < 64; d <<= 1) {
    uint32_t n = __shfl_up(incl, d, 64);
    if (lane >= (uint32_t)d) incl += n;
  }
  if (lane == 63u) wt[wid] = incl;
  __syncthreads();
  uint32_t wbase = 0u;
  for (uint32_t w = 0; w < wid; ++w) wbase += wt[w];
  uint32_t base = s_base + wbase + (incl - s);
  ((uint4*)offs)[b0 >> 2] = make_uint4(base, base + c.x, base + c.x + c.y,
                                       base + c.x + c.y + c.z);
}

// ---------- range-walk writer: dense stores over each wave's 8-key union ----------
__global__ __launch_bounds__(256) void k_write_range(const uint32_t* __restrict__ offs,
                                                     float4* __restrict__ out4) {
  __shared__ uint32_t s_off[33];
  uint32_t tid = threadIdx.x, blk = blockIdx.x;
  if (tid < 33u) {
    uint32_t k = blk * 32u + tid;
    s_off[tid] = (k < BINS) ? offs[k] : SEQN;
  }
  __syncthreads();
  uint32_t lane = tid & 63u, wid = tid >> 6;
  uint32_t kbase = blk * 32u + wid * 8u;
  uint32_t q0 = s_off[wid * 8u] * 4u;         // multiple of 4 -> g&3 == lane&3 forever
  uint32_t q8 = s_off[wid * 8u + 8u] * 4u;
  uint32_t b1 = s_off[wid * 8u + 1u] * 4u, b2 = s_off[wid * 8u + 2u] * 4u;
  uint32_t b3 = s_off[wid * 8u + 3u] * 4u, b4 = s_off[wid * 8u + 4u] * 4u;
  uint32_t b5 = s_off[wid * 8u + 5u] * 4u, b6 = s_off[wid * 8u + 6u] * 4u;
  uint32_t b7 = s_off[wid * 8u + 7u] * 4u;
  uint32_t sh = 12u - ((lane & 3u) << 2);
  for (uint32_t g = q0 + lane; g < q8; g += 64u) {
    uint32_t kl = (uint32_t)(g >= b1) + (uint32_t)(g >= b2) + (uint32_t)(g >= b3) +
                  (uint32_t)(g >= b4) + (uint32_t)(g >= b5) + (uint32_t)(g >= b6) +
                  (uint32_t)(g >= b7);
    uint32_t key = kbase + kl;
    uint32_t nib = (key >> sh) & 15u;
    float4 pat;
    pat.x = (float)((nib >> 3) & 1u);
    pat.y = (float)((nib >> 2) & 1u);
    pat.z = (float)((nib >> 1) & 1u);
    pat.w = (float)(nib & 1u);
    out4[g] = pat;
  }
}

extern "C" void kernel_launch(void* const* d_in, const int* in_sizes, int n_in,
                              void* d_out, int out_size, void* d_ws, size_t ws_size,
                              hipStream_t stream) {
  const float4* in4 = (const float4*)d_in[0];
  float4* out4 = (float4*)d_out;
  uint32_t* hist = (uint32_t*)d_ws;               // 65536 u32 (fallback only)
  uint32_t* offs = hist + BINS;                   // 65536 u32
  uint32_t* blkTot = offs + BINS;                 // 1024 u32 (fallback only)
  uint32_t* partial = blkTot + 1024u;             // NBLK * QWORDS u32 = 16 MiB
  uint32_t* groupSum = partial + (size_t)NBLK * QWORDS;  // 256*64 u32 = 64 KiB

  size_t need = ((size_t)2 * BINS + 1024u + (size_t)NBLK * QWORDS + NBLK * 64u) * 4u;
  if (ws_size >= need) {
    k_hist_lds<<<NBLK, NTHR, 0, stream>>>(in4, partial, groupSum);
    k_redscan<<<64, NTHR, 0, stream>>>(partial, groupSum, offs);
  } else {
    k_zero<<<BINS / 256, 256, 0, stream>>>(hist, blkTot);
    k_hist<<<SEQN / 256, 256, 0, stream>>>(in4, hist);
    k_scan1<<<64, 256, 0, stream>>>(hist, blkTot);
    k_scanB<<<64, 256, 0, stream>>>(hist, blkTot, offs);
  }
  k_write_range<<<BINS / 32, 256, 0, stream>>>(offs, out4);
}